// Round 5
// baseline (846.040 us; speedup 1.0000x reference)
//
#include <hip/hip_runtime.h>
#include <math.h>

#define N_TASKS 200000
#define N_DATA  100000
#define N_DEV   4
#define E_TD    800000
#define E_TT    1600000
#define E_DV    800000
#define E_ALL   (E_TD + E_TT + E_DV)

struct __align__(8) Payload { int src; float scal; };  // scal = exp(leaky(full logit))

// ---- workspace layout (units: 4-byte words) — IDENTICAL footprint to the
// round-4 passing kernel (ends at OFF_PAY + 2*E_ALL = 108.4 MB).
#define OFF_HS_TD   0                          // 100000*64
#define OFF_HS_TT   (OFF_HS_TD + 6400000)      // 200000*64
#define OFF_HS_DV   (OFF_HS_TT + 12800000)     // 4*64 -> 256
#define OFF_SS_TD   (OFF_HS_DV + 256)          // 100000
#define OFF_SS_TT   (OFF_SS_TD + 100000)       // 200000
#define OFF_SS_DV   (OFF_SS_TT + 200000)       // 4 -> 8
#define OFF_WDAD    (OFF_SS_DV + 8)            // 3*12 -> 64
#define OFF_WEA     (OFF_WDAD + 64)            // 6 -> 8
#define OFF_CNT     (OFF_WEA + 8)              // 3*N_TASKS = 600000
#define OFF_PTR     (OFF_CNT + 600000)         // 600000
#define OFF_AUX     (OFF_PTR + 600000)         // 1024
#define OFF_PAY     (OFF_AUX + 1024)           // 3.2M payloads * 2 words
#define SCAN_N      600000
#define SCAN_BLOCKS ((SCAN_N + 1023) / 1024)   // 586

// pre_kernel grid partition — histogram FIRST (it's the long pole; the
// GEMV blocks then overlap it instead of preceding it).
#define CNT_B   12500                          // E_ALL/256
#define HS_TD_B 25000                          // N_DATA*64/256
#define HS_TT_B 50000                          // N_TASKS*64/256
#define PRE_B   (CNT_B + HS_TD_B + HS_TT_B + 1)

// Fold Wd@a_d (per relation, 12 floats) and We@a_e (3+1+2 floats) once.
__global__ void prep_kernel(const float* Wd_td, const float* ad_td,
                            const float* Wd_tt, const float* ad_tt,
                            const float* Wd_dv, const float* ad_dv,
                            const float* We_td, const float* ae_td,
                            const float* We_tt, const float* ae_tt,
                            const float* We_dv, const float* ae_dv,
                            float* wdad, float* wea) {
    int t = threadIdx.x;
    if (t < 36) {
        int r = t / 12, k = t % 12;
        const float* Wd = r == 0 ? Wd_td : (r == 1 ? Wd_tt : Wd_dv);
        const float* ad = r == 0 ? ad_td : (r == 1 ? ad_tt : ad_dv);
        float acc = 0.f;
        for (int c = 0; c < 64; ++c) acc += Wd[k * 64 + c] * ad[c];
        wdad[r * 12 + k] = acc;
    } else if (t < 42) {
        int i = t - 36;
        int r, k;
        if (i < 3)      { r = 0; k = i; }
        else if (i < 4) { r = 1; k = 0; }
        else            { r = 2; k = i - 4; }
        const float* We = r == 0 ? We_td : (r == 1 ? We_tt : We_dv);
        const float* ae = r == 0 ? ae_td : (r == 1 ? ae_tt : ae_dv);
        float acc = 0.f;
        for (int c = 0; c < 64; ++c) acc += We[k * 64 + c] * ae[c];
        wea[i] = acc;
    }
}

// hs = x_src @ Ws  [Ns,64]; ss = hs @ a_s  [Ns]. One wave per source node.
// DS is a COMPILE-TIME constant so the x-load loop fully unrolls -> all
// loads issue together (one vmcnt wait) instead of DS dependent stalls.
template <int DS>
__device__ __forceinline__ void hs_body(const float* __restrict__ x, int Ns,
                                        const float* __restrict__ Ws, const float* __restrict__ a_s,
                                        float* __restrict__ hs, float* __restrict__ ss,
                                        int blk, int tid) {
    int gid = blk * 256 + tid;
    int s = gid >> 6;
    int lane = gid & 63;
    if (s >= Ns) return;
    float xv[DS];
    #pragma unroll
    for (int k = 0; k < DS; ++k) xv[k] = x[(size_t)s * DS + k];
    float acc = 0.f;
    #pragma unroll
    for (int k = 0; k < DS; ++k) acc = fmaf(xv[k], Ws[k * 64 + lane], acc);
    hs[(size_t)s * 64 + lane] = acc;
    float t = acc * a_s[lane];
    for (int off = 32; off; off >>= 1) t += __shfl_down(t, off, 64);
    if (lane == 0) ss[s] = t;
}

// Fused pre-pass: merged dst histogram (first -> starts immediately, it's the
// latency-bound long pole) + hs GEMVs for all 3 relations filling in behind.
__global__ __launch_bounds__(256) void pre_kernel(
    const float* __restrict__ x_data, const float* __restrict__ x_tasks, const float* __restrict__ x_devices,
    const float* __restrict__ Ws_td, const float* __restrict__ as_td,
    const float* __restrict__ Ws_tt, const float* __restrict__ as_tt,
    const float* __restrict__ Ws_dv, const float* __restrict__ as_dv,
    float* __restrict__ hs_td, float* __restrict__ ss_td,
    float* __restrict__ hs_tt, float* __restrict__ ss_tt,
    float* __restrict__ hs_dv, float* __restrict__ ss_dv,
    const int* __restrict__ dst_td, const int* __restrict__ dst_tt, const int* __restrict__ dst_dv,
    int* __restrict__ cnt) {
    int b = blockIdx.x, tid = threadIdx.x;
    if (b < CNT_B) {
        int i = b * 256 + tid;
        if (i < E_TD) {
            atomicAdd(&cnt[dst_td[i]], 1);
        } else if (i < E_TD + E_TT) {
            atomicAdd(&cnt[N_TASKS + dst_tt[i - E_TD]], 1);
        } else if (i < E_ALL) {
            atomicAdd(&cnt[2 * N_TASKS + dst_dv[i - E_TD - E_TT]], 1);
        }
        return;
    }
    b -= CNT_B;
    if (b < HS_TD_B) { hs_body<5>(x_data, N_DATA, Ws_td, as_td, hs_td, ss_td, b, tid); return; }
    b -= HS_TD_B;
    if (b < HS_TT_B) { hs_body<12>(x_tasks, N_TASKS, Ws_tt, as_tt, hs_tt, ss_tt, b, tid); return; }
    b -= HS_TT_B;
    hs_body<12>(x_devices, N_DEV, Ws_dv, as_dv, hs_dv, ss_dv, 0, tid);
}

// ---- 2-kernel exclusive scan over 600000 ints (block-local; the per-block
// base aux[] is folded into consumers instead of a third pass) ----
__global__ void scan1(const int* __restrict__ cnt, int* __restrict__ ptr,
                      int* __restrict__ aux, int n) {
    __shared__ int s[256];
    int b = blockIdx.x, t = threadIdx.x;
    int base = b * 1024 + t * 4;
    int v0 = base + 0 < n ? cnt[base + 0] : 0;
    int v1 = base + 1 < n ? cnt[base + 1] : 0;
    int v2 = base + 2 < n ? cnt[base + 2] : 0;
    int v3 = base + 3 < n ? cnt[base + 3] : 0;
    int tsum = v0 + v1 + v2 + v3;
    s[t] = tsum;
    __syncthreads();
    for (int off = 1; off < 256; off <<= 1) {
        int x = (t >= off) ? s[t - off] : 0;
        __syncthreads();
        s[t] += x;
        __syncthreads();
    }
    int p = s[t] - tsum;  // exclusive prefix within block
    if (t == 255) aux[b] = s[255];
    if (base + 0 < n) ptr[base + 0] = p; p += v0;
    if (base + 1 < n) ptr[base + 1] = p; p += v1;
    if (base + 2 < n) ptr[base + 2] = p; p += v2;
    if (base + 3 < n) ptr[base + 3] = p;
}

__global__ void scan2(int* __restrict__ aux, int nb) {
    __shared__ int s[256];
    int t = threadIdx.x;
    int carry = 0;
    for (int base = 0; base < nb; base += 256) {
        int i = base + t;
        int v = i < nb ? aux[i] : 0;
        s[t] = v;
        __syncthreads();
        for (int off = 1; off < 256; off <<= 1) {
            int x = (t >= off) ? s[t - off] : 0;
            __syncthreads();
            s[t] += x;
            __syncthreads();
        }
        int excl = s[t] - v + carry;
        if (i < nb) aux[i] = excl;
        int total = s[255];
        __syncthreads();
        carry += total;
    }
}

// Merged scatter: (src, exp(leaky(full logit))) into CSR payload slots.
// ptr[] holds the BLOCK-LOCAL exclusive prefix; global position = local rank
// + aux[seg>>10] (aux = 2.3 KB -> L1-resident gather).
__global__ void scatter_all(const int* __restrict__ src_td, const int* __restrict__ dst_td, const float* __restrict__ ea_td,
                            const int* __restrict__ src_tt, const int* __restrict__ dst_tt, const float* __restrict__ ea_tt,
                            const int* __restrict__ src_dv, const int* __restrict__ dst_dv, const float* __restrict__ ea_dv,
                            const float* __restrict__ wea, const float* __restrict__ wdad,
                            const float* __restrict__ x_tasks,
                            const float* __restrict__ ss_td, const float* __restrict__ ss_tt, const float* __restrict__ ss_dv,
                            int* __restrict__ cursor, const int* __restrict__ aux,
                            Payload* __restrict__ payload) {
    int i = blockIdx.x * blockDim.x + threadIdx.x;
    if (i >= E_ALL) return;
    int s, dnode, r;
    float sc;
    if (i < E_TD) {
        int e = i;
        r = 0;
        sc = ea_td[(size_t)e * 3 + 0] * wea[0] + ea_td[(size_t)e * 3 + 1] * wea[1] + ea_td[(size_t)e * 3 + 2] * wea[2];
        s = src_td[e];
        sc += ss_td[s];
        dnode = dst_td[e];
    } else if (i < E_TD + E_TT) {
        int e = i - E_TD;
        r = 1;
        sc = ea_tt[e] * wea[3];
        s = src_tt[e];
        sc += ss_tt[s];
        dnode = dst_tt[e];
    } else {
        int e = i - E_TD - E_TT;
        r = 2;
        sc = ea_dv[(size_t)e * 2 + 0] * wea[4] + ea_dv[(size_t)e * 2 + 1] * wea[5];
        s = src_dv[e];
        sc += ss_dv[s];
        dnode = dst_dv[e];
    }
    // dst-side attention term: x_tasks[dnode] (12 floats, 16B-aligned) @ wdad[r]
    const float4* xt4 = (const float4*)(x_tasks + (size_t)dnode * 12);
    float4 xa = xt4[0], xb = xt4[1], xc = xt4[2];
    const float* wd = wdad + r * 12;
    sc += xa.x * wd[0] + xa.y * wd[1] + xa.z * wd[2] + xa.w * wd[3]
        + xb.x * wd[4] + xb.y * wd[5] + xb.z * wd[6] + xb.w * wd[7]
        + xc.x * wd[8] + xc.y * wd[9] + xc.z * wd[10] + xc.w * wd[11];
    float lg = sc > 0.f ? sc : 0.2f * sc;  // leaky_relu(logit, 0.2)
    int dseg = r * N_TASKS + dnode;
    int pos = atomicAdd(&cursor[dseg], 1) + aux[dseg >> 10];
    Payload p; p.src = s; p.scal = __expf(lg);
    payload[pos] = p;
}

// One WAVE per task node (4 per 256-block), channel = lane, no LDS/barriers.
// The 3 relations are processed INTERLEAVED in one branch-free loop over
// max(c0,c1,c2) iterations: 3 independent payload->gather chains in flight
// per iteration (x unroll 2 = 6) instead of one serial chain of c0+c1+c2.
// Exhausted relations clamp to payload[0] / hs[0] (L1-hot) with weight 0.
__global__ __launch_bounds__(256) void fused_node_kernel(
    const float* __restrict__ x_tasks,
    const int* __restrict__ ptr, const int* __restrict__ cnt, const int* __restrict__ aux,
    const Payload* __restrict__ payload,
    const float* __restrict__ hs_td, const float* __restrict__ hs_tt, const float* __restrict__ hs_dv,
    const float* __restrict__ Wr_td, const float* __restrict__ Wr_tt, const float* __restrict__ Wr_dv,
    const float* __restrict__ b_td, const float* __restrict__ b_tt, const float* __restrict__ b_dv,
    const float* __restrict__ ln_g, const float* __restrict__ ln_b,
    float* __restrict__ out) {
    int wid = (blockIdx.x * blockDim.x + threadIdx.x) >> 6;
    if (wid >= N_TASKS) return;
    int d = __builtin_amdgcn_readfirstlane(wid);  // force SGPR -> scalar loads
    int lane = threadIdx.x & 63;

    int i0 = d, i1 = N_TASKS + d, i2 = 2 * N_TASKS + d;
    int end0 = ptr[i0] + aux[i0 >> 10]; int c0 = cnt[i0]; int beg0 = end0 - c0;
    int end1 = ptr[i1] + aux[i1 >> 10]; int c1 = cnt[i1]; int beg1 = end1 - c1;
    int end2 = ptr[i2] + aux[i2 >> 10]; int c2 = cnt[i2]; int beg2 = end2 - c2;
    int n = max(max(c0, c1), c2);

    float acc0 = 0.f, ws0 = 0.f, acc1 = 0.f, ws1 = 0.f, acc2 = 0.f, ws2 = 0.f;
    #pragma unroll 2
    for (int i = 0; i < n; ++i) {
        bool v0 = i < c0, v1 = i < c1, v2 = i < c2;
        Payload p0 = payload[v0 ? beg0 + i : 0];
        Payload p1 = payload[v1 ? beg1 + i : 0];
        Payload p2 = payload[v2 ? beg2 + i : 0];
        int s0 = v0 ? p0.src : 0;  float f0 = v0 ? p0.scal : 0.f;
        int s1 = v1 ? p1.src : 0;  float f1 = v1 ? p1.scal : 0.f;
        int s2 = v2 ? p2.src : 0;  float f2 = v2 ? p2.scal : 0.f;
        acc0 = fmaf(f0, hs_td[(size_t)s0 * 64 + lane], acc0); ws0 += f0;
        acc1 = fmaf(f1, hs_tt[(size_t)s1 * 64 + lane], acc1); ws1 += f1;
        acc2 = fmaf(f2, hs_dv[(size_t)s2 * 64 + lane], acc2); ws2 += f2;
    }

    const float* xp = x_tasks + (size_t)d * 12;   // uniform base
    float xl = lane < 12 ? xp[lane] : 0.f;        // per-lane copy for LN

    // residual + bias, channel = lane
    float r0 = b_td[lane], r1 = b_tt[lane], r2 = b_dv[lane];
    #pragma unroll
    for (int k = 0; k < 12; ++k) {
        float xk = xp[k];
        r0 = fmaf(xk, Wr_td[k * 64 + lane], r0);
        r1 = fmaf(xk, Wr_tt[k * 64 + lane], r1);
        r2 = fmaf(xk, Wr_dv[k * 64 + lane], r2);
    }
    float a0 = acc0 / (ws0 + 1e-16f) + r0;
    float a1 = acc1 / (ws1 + 1e-16f) + r1;
    float a2 = acc2 / (ws2 + 1e-16f) + r2;

    // LayerNorm over 204 = 12 (x) + 3*64, fully in-wave
    float sum = a0 + a1 + a2 + xl;
    float sq  = a0 * a0 + a1 * a1 + a2 * a2 + xl * xl;
    #pragma unroll
    for (int off = 1; off < 64; off <<= 1) {
        sum += __shfl_xor(sum, off, 64);
        sq  += __shfl_xor(sq, off, 64);
    }
    float mu = sum * (1.f / 204.f);
    float rstd = rsqrtf(sq * (1.f / 204.f) - mu * mu + 1e-5f);

    float* op = out + (size_t)d * 204;
    if (lane < 12) {
        float y = (xl - mu) * rstd * ln_g[lane] + ln_b[lane];
        op[lane] = y > 0.f ? y : 0.01f * y;
    }
    {
        float y = (a0 - mu) * rstd * ln_g[12 + lane] + ln_b[12 + lane];
        op[12 + lane] = y > 0.f ? y : 0.01f * y;
    }
    {
        float y = (a1 - mu) * rstd * ln_g[76 + lane] + ln_b[76 + lane];
        op[76 + lane] = y > 0.f ? y : 0.01f * y;
    }
    {
        float y = (a2 - mu) * rstd * ln_g[140 + lane] + ln_b[140 + lane];
        op[140 + lane] = y > 0.f ? y : 0.01f * y;
    }
}

extern "C" void kernel_launch(void* const* d_in, const int* in_sizes, int n_in,
                              void* d_out, int out_size, void* d_ws, size_t ws_size,
                              hipStream_t stream) {
    const float* x_tasks   = (const float*)d_in[0];
    const float* x_data    = (const float*)d_in[1];
    const float* x_devices = (const float*)d_in[2];
    const int*   src_td = (const int*)d_in[3];
    const int*   dst_td = (const int*)d_in[4];
    const float* eattr_td = (const float*)d_in[5];
    const int*   src_tt = (const int*)d_in[6];
    const int*   dst_tt = (const int*)d_in[7];
    const float* eattr_tt = (const float*)d_in[8];
    const int*   src_dv = (const int*)d_in[9];
    const int*   dst_dv = (const int*)d_in[10];
    const float* eattr_dv = (const float*)d_in[11];
    const float* Ws_td = (const float*)d_in[12];
    const float* Wd_td = (const float*)d_in[13];
    const float* We_td = (const float*)d_in[14];
    const float* as_td = (const float*)d_in[15];
    const float* ad_td = (const float*)d_in[16];
    const float* ae_td = (const float*)d_in[17];
    const float* Wr_td = (const float*)d_in[18];
    const float* b_td  = (const float*)d_in[19];
    const float* Ws_tt = (const float*)d_in[20];
    const float* Wd_tt = (const float*)d_in[21];
    const float* We_tt = (const float*)d_in[22];
    const float* as_tt = (const float*)d_in[23];
    const float* ad_tt = (const float*)d_in[24];
    const float* ae_tt = (const float*)d_in[25];
    const float* Wr_tt = (const float*)d_in[26];
    const float* b_tt  = (const float*)d_in[27];
    const float* Ws_dv = (const float*)d_in[28];
    const float* Wd_dv = (const float*)d_in[29];
    const float* We_dv = (const float*)d_in[30];
    const float* as_dv = (const float*)d_in[31];
    const float* ad_dv = (const float*)d_in[32];
    const float* ae_dv = (const float*)d_in[33];
    const float* Wr_dv = (const float*)d_in[34];
    const float* b_dv  = (const float*)d_in[35];
    const float* ln_g  = (const float*)d_in[36];
    const float* ln_b  = (const float*)d_in[37];

    float* ws = (float*)d_ws;
    float* hs_td = ws + OFF_HS_TD;
    float* hs_tt = ws + OFF_HS_TT;
    float* hs_dv = ws + OFF_HS_DV;
    float* ss_td = ws + OFF_SS_TD;
    float* ss_tt = ws + OFF_SS_TT;
    float* ss_dv = ws + OFF_SS_DV;
    float* wdad  = ws + OFF_WDAD;
    float* wea   = ws + OFF_WEA;
    int*   cnt   = (int*)(ws + OFF_CNT);
    int*   ptr   = (int*)(ws + OFF_PTR);
    int*   aux   = (int*)(ws + OFF_AUX);
    Payload* pay = (Payload*)(ws + OFF_PAY);

    float* outp = (float*)d_out;

    hipMemsetAsync(cnt, 0, SCAN_N * sizeof(int), stream);

    prep_kernel<<<1, 64, 0, stream>>>(Wd_td, ad_td, Wd_tt, ad_tt, Wd_dv, ad_dv,
                                      We_td, ae_td, We_tt, ae_tt, We_dv, ae_dv,
                                      wdad, wea);

    pre_kernel<<<PRE_B, 256, 0, stream>>>(
        x_data, x_tasks, x_devices,
        Ws_td, as_td, Ws_tt, as_tt, Ws_dv, as_dv,
        hs_td, ss_td, hs_tt, ss_tt, hs_dv, ss_dv,
        dst_td, dst_tt, dst_dv, cnt);

    scan1<<<SCAN_BLOCKS, 256, 0, stream>>>(cnt, ptr, aux, SCAN_N);
    scan2<<<1, 256, 0, stream>>>(aux, SCAN_BLOCKS);

    scatter_all<<<(E_ALL + 255) / 256, 256, 0, stream>>>(
        src_td, dst_td, eattr_td, src_tt, dst_tt, eattr_tt, src_dv, dst_dv, eattr_dv,
        wea, wdad, x_tasks, ss_td, ss_tt, ss_dv, ptr, aux, pay);

    fused_node_kernel<<<(N_TASKS * 64 + 255) / 256, 256, 0, stream>>>(
        x_tasks, ptr, cnt, aux, pay, hs_td, hs_tt, hs_dv,
        Wr_td, Wr_tt, Wr_dv, b_td, b_tt, b_dv, ln_g, ln_b, outp);
}

// Round 6
// 794.074 us; speedup vs baseline: 1.0654x; 1.0654x over previous
//
#include <hip/hip_runtime.h>
#include <math.h>

#define N_TASKS 200000
#define N_DATA  100000
#define N_DEV   4
#define E_TD    800000
#define E_TT    1600000
#define E_DV    800000
#define E_ALL   (E_TD + E_TT + E_DV)

struct __align__(8) Payload { int src; float scal; };  // scal = ss[src] + ea@wea (raw partial logit)

// ---- workspace layout (units: 4-byte words) — IDENTICAL footprint to the
// round-4 passing kernel (ends at OFF_PAY + 2*E_ALL = 108.4 MB).
#define OFF_HS_TD   0                          // 100000*64
#define OFF_HS_TT   (OFF_HS_TD + 6400000)      // 200000*64
#define OFF_HS_DV   (OFF_HS_TT + 12800000)     // 4*64 -> 256
#define OFF_SS_TD   (OFF_HS_DV + 256)          // 100000
#define OFF_SS_TT   (OFF_SS_TD + 100000)       // 200000
#define OFF_SS_DV   (OFF_SS_TT + 200000)       // 4 -> 8
#define OFF_WDAD    (OFF_SS_DV + 8)            // 3*12 -> 64
#define OFF_WEA     (OFF_WDAD + 64)            // 6 -> 8
#define OFF_CNT     (OFF_WEA + 8)              // 3*N_TASKS = 600000
#define OFF_PTR     (OFF_CNT + 600000)         // 600000
#define OFF_AUX     (OFF_PTR + 600000)         // 1024
#define OFF_PAY     (OFF_AUX + 1024)           // 3.2M payloads * 2 words
#define SCAN_N      600000
#define SCAN_BLOCKS ((SCAN_N + 1023) / 1024)   // 586

// pre_kernel grid partition — histogram FIRST (it's the latency-bound long
// pole; the GEMV blocks then overlap it).
#define CNT_B   12500                          // E_ALL/256
#define HS_TD_B 25000                          // N_DATA*64/256
#define HS_TT_B 50000                          // N_TASKS*64/256
#define PRE_B   (CNT_B + HS_TD_B + HS_TT_B + 1)

// Fold Wd@a_d (per relation, 12 floats) and We@a_e (3+1+2 floats) once.
__global__ void prep_kernel(const float* Wd_td, const float* ad_td,
                            const float* Wd_tt, const float* ad_tt,
                            const float* Wd_dv, const float* ad_dv,
                            const float* We_td, const float* ae_td,
                            const float* We_tt, const float* ae_tt,
                            const float* We_dv, const float* ae_dv,
                            float* wdad, float* wea) {
    int t = threadIdx.x;
    if (t < 36) {
        int r = t / 12, k = t % 12;
        const float* Wd = r == 0 ? Wd_td : (r == 1 ? Wd_tt : Wd_dv);
        const float* ad = r == 0 ? ad_td : (r == 1 ? ad_tt : ad_dv);
        float acc = 0.f;
        for (int c = 0; c < 64; ++c) acc += Wd[k * 64 + c] * ad[c];
        wdad[r * 12 + k] = acc;
    } else if (t < 42) {
        int i = t - 36;
        int r, k;
        if (i < 3)      { r = 0; k = i; }
        else if (i < 4) { r = 1; k = 0; }
        else            { r = 2; k = i - 4; }
        const float* We = r == 0 ? We_td : (r == 1 ? We_tt : We_dv);
        const float* ae = r == 0 ? ae_td : (r == 1 ? ae_tt : ae_dv);
        float acc = 0.f;
        for (int c = 0; c < 64; ++c) acc += We[k * 64 + c] * ae[c];
        wea[i] = acc;
    }
}

// hs = x_src @ Ws  [Ns,64]; ss = hs @ a_s  [Ns]. One wave per source node.
// DS is a COMPILE-TIME constant so the x-load loop fully unrolls.
template <int DS>
__device__ __forceinline__ void hs_body(const float* __restrict__ x, int Ns,
                                        const float* __restrict__ Ws, const float* __restrict__ a_s,
                                        float* __restrict__ hs, float* __restrict__ ss,
                                        int blk, int tid) {
    int gid = blk * 256 + tid;
    int s = gid >> 6;
    int lane = gid & 63;
    if (s >= Ns) return;
    float xv[DS];
    #pragma unroll
    for (int k = 0; k < DS; ++k) xv[k] = x[(size_t)s * DS + k];
    float acc = 0.f;
    #pragma unroll
    for (int k = 0; k < DS; ++k) acc = fmaf(xv[k], Ws[k * 64 + lane], acc);
    hs[(size_t)s * 64 + lane] = acc;
    float t = acc * a_s[lane];
    for (int off = 32; off; off >>= 1) t += __shfl_down(t, off, 64);
    if (lane == 0) ss[s] = t;
}

// Fused pre-pass: merged dst histogram + hs GEMVs for all 3 relations.
__global__ __launch_bounds__(256) void pre_kernel(
    const float* __restrict__ x_data, const float* __restrict__ x_tasks, const float* __restrict__ x_devices,
    const float* __restrict__ Ws_td, const float* __restrict__ as_td,
    const float* __restrict__ Ws_tt, const float* __restrict__ as_tt,
    const float* __restrict__ Ws_dv, const float* __restrict__ as_dv,
    float* __restrict__ hs_td, float* __restrict__ ss_td,
    float* __restrict__ hs_tt, float* __restrict__ ss_tt,
    float* __restrict__ hs_dv, float* __restrict__ ss_dv,
    const int* __restrict__ dst_td, const int* __restrict__ dst_tt, const int* __restrict__ dst_dv,
    int* __restrict__ cnt) {
    int b = blockIdx.x, tid = threadIdx.x;
    if (b < CNT_B) {
        int i = b * 256 + tid;
        if (i < E_TD) {
            atomicAdd(&cnt[dst_td[i]], 1);
        } else if (i < E_TD + E_TT) {
            atomicAdd(&cnt[N_TASKS + dst_tt[i - E_TD]], 1);
        } else if (i < E_ALL) {
            atomicAdd(&cnt[2 * N_TASKS + dst_dv[i - E_TD - E_TT]], 1);
        }
        return;
    }
    b -= CNT_B;
    if (b < HS_TD_B) { hs_body<5>(x_data, N_DATA, Ws_td, as_td, hs_td, ss_td, b, tid); return; }
    b -= HS_TD_B;
    if (b < HS_TT_B) { hs_body<12>(x_tasks, N_TASKS, Ws_tt, as_tt, hs_tt, ss_tt, b, tid); return; }
    b -= HS_TT_B;
    hs_body<12>(x_devices, N_DEV, Ws_dv, as_dv, hs_dv, ss_dv, 0, tid);
}

// ---- 2-kernel exclusive scan over 600000 ints (block-local; the per-block
// base aux[] is folded into consumers) ----
__global__ void scan1(const int* __restrict__ cnt, int* __restrict__ ptr,
                      int* __restrict__ aux, int n) {
    __shared__ int s[256];
    int b = blockIdx.x, t = threadIdx.x;
    int base = b * 1024 + t * 4;
    int v0 = base + 0 < n ? cnt[base + 0] : 0;
    int v1 = base + 1 < n ? cnt[base + 1] : 0;
    int v2 = base + 2 < n ? cnt[base + 2] : 0;
    int v3 = base + 3 < n ? cnt[base + 3] : 0;
    int tsum = v0 + v1 + v2 + v3;
    s[t] = tsum;
    __syncthreads();
    for (int off = 1; off < 256; off <<= 1) {
        int x = (t >= off) ? s[t - off] : 0;
        __syncthreads();
        s[t] += x;
        __syncthreads();
    }
    int p = s[t] - tsum;  // exclusive prefix within block
    if (t == 255) aux[b] = s[255];
    if (base + 0 < n) ptr[base + 0] = p; p += v0;
    if (base + 1 < n) ptr[base + 1] = p; p += v1;
    if (base + 2 < n) ptr[base + 2] = p; p += v2;
    if (base + 3 < n) ptr[base + 3] = p;
}

__global__ void scan2(int* __restrict__ aux, int nb) {
    __shared__ int s[256];
    int t = threadIdx.x;
    int carry = 0;
    for (int base = 0; base < nb; base += 256) {
        int i = base + t;
        int v = i < nb ? aux[i] : 0;
        s[t] = v;
        __syncthreads();
        for (int off = 1; off < 256; off <<= 1) {
            int x = (t >= off) ? s[t - off] : 0;
            __syncthreads();
            s[t] += x;
            __syncthreads();
        }
        int excl = s[t] - v + carry;
        if (i < nb) aux[i] = excl;
        int total = s[255];
        __syncthreads();
        carry += total;
    }
}

// Merged scatter: (src, raw partial logit ss[src] + ea@wea) into CSR slots.
// The dst-side term and exp(leaky(.)) moved to fused_node_kernel: the dst
// term is SEGMENT-CONSTANT, so fused computes it once per (node, relation)
// instead of a 48B random x_tasks gather per EDGE here (-~200MB of traffic).
__global__ void scatter_all(const int* __restrict__ src_td, const int* __restrict__ dst_td, const float* __restrict__ ea_td,
                            const int* __restrict__ src_tt, const int* __restrict__ dst_tt, const float* __restrict__ ea_tt,
                            const int* __restrict__ src_dv, const int* __restrict__ dst_dv, const float* __restrict__ ea_dv,
                            const float* __restrict__ wea,
                            const float* __restrict__ ss_td, const float* __restrict__ ss_tt, const float* __restrict__ ss_dv,
                            int* __restrict__ cursor, const int* __restrict__ aux,
                            Payload* __restrict__ payload) {
    int i = blockIdx.x * blockDim.x + threadIdx.x;
    if (i >= E_ALL) return;
    int s, dseg;
    float sc;
    if (i < E_TD) {
        int e = i;
        sc = ea_td[(size_t)e * 3 + 0] * wea[0] + ea_td[(size_t)e * 3 + 1] * wea[1] + ea_td[(size_t)e * 3 + 2] * wea[2];
        s = src_td[e];
        sc += ss_td[s];
        dseg = dst_td[e];
    } else if (i < E_TD + E_TT) {
        int e = i - E_TD;
        sc = ea_tt[e] * wea[3];
        s = src_tt[e];
        sc += ss_tt[s];
        dseg = N_TASKS + dst_tt[e];
    } else {
        int e = i - E_TD - E_TT;
        sc = ea_dv[(size_t)e * 2 + 0] * wea[4] + ea_dv[(size_t)e * 2 + 1] * wea[5];
        s = src_dv[e];
        sc += ss_dv[s];
        dseg = 2 * N_TASKS + dst_dv[e];
    }
    int pos = atomicAdd(&cursor[dseg], 1) + aux[dseg >> 10];
    Payload p; p.src = s; p.scal = sc;
    payload[pos] = p;
}

// Per-relation GAT aggregation for ONE node by ONE wave, channel = lane.
// (Round-4 proven structure: serial relations, unroll 4 -> 4 independent
// payload->gather chains in flight. The round-5 interleave regressed.)
// Edge weight w = exp(leaky(scal + c)) where c = x[d]@wdad[r] is computed
// ONCE per segment (uniform); per edge it costs ~4 wave-wide VALU ops on a
// kernel with VALU slack. Denominator accumulates identically in all lanes.
__device__ __forceinline__ float gat_wave(
    int d, int r, int lane,
    const int* __restrict__ ptr, const int* __restrict__ cnt, const int* __restrict__ aux,
    const Payload* __restrict__ payload,
    const float* __restrict__ hs, const float* __restrict__ Wr, const float* __restrict__ bb,
    const float* __restrict__ xp, const float* __restrict__ wdad) {
    int idx = r * N_TASKS + d;
    int end = ptr[idx] + aux[idx >> 10];   // ptr is block-local; aux folds the base
    int beg = end - cnt[idx];
    // segment-constant dst-side attention term
    float c = 0.f;
    #pragma unroll
    for (int k = 0; k < 12; ++k) c = fmaf(xp[k], wdad[r * 12 + k], c);
    float acc = 0.f, wsum = 0.f;
    #pragma unroll 4
    for (int e = beg; e < end; ++e) {
        Payload p = payload[e];            // wave-uniform -> scalar load
        float sc = p.scal + c;
        float lg = sc > 0.f ? sc : 0.2f * sc;
        float w = __expf(lg);
        acc = fmaf(w, hs[(size_t)p.src * 64 + lane], acc);
        wsum += w;
    }
    // residual + bias, channel = lane
    float res = bb[lane];
    #pragma unroll
    for (int k = 0; k < 12; ++k) res = fmaf(xp[k], Wr[k * 64 + lane], res);
    return acc / (wsum + 1e-16f) + res;
}

// One WAVE per task node (4 nodes per 256-thread block). No LDS, no barriers.
// LayerNorm over 204 channels entirely in-wave via butterfly shuffles.
__global__ __launch_bounds__(256) void fused_node_kernel(
    const float* __restrict__ x_tasks,
    const int* __restrict__ ptr, const int* __restrict__ cnt, const int* __restrict__ aux,
    const Payload* __restrict__ payload,
    const float* __restrict__ hs_td, const float* __restrict__ hs_tt, const float* __restrict__ hs_dv,
    const float* __restrict__ wdad,
    const float* __restrict__ Wr_td, const float* __restrict__ Wr_tt, const float* __restrict__ Wr_dv,
    const float* __restrict__ b_td, const float* __restrict__ b_tt, const float* __restrict__ b_dv,
    const float* __restrict__ ln_g, const float* __restrict__ ln_b,
    float* __restrict__ out) {
    int wid = (blockIdx.x * blockDim.x + threadIdx.x) >> 6;
    if (wid >= N_TASKS) return;
    int d = __builtin_amdgcn_readfirstlane(wid);  // force SGPR -> scalar loads
    int lane = threadIdx.x & 63;

    const float* xp = x_tasks + (size_t)d * 12;   // uniform base
    float xl = lane < 12 ? xp[lane] : 0.f;        // per-lane copy for LN

    float a0 = gat_wave(d, 0, lane, ptr, cnt, aux, payload, hs_td, Wr_td, b_td, xp, wdad);
    float a1 = gat_wave(d, 1, lane, ptr, cnt, aux, payload, hs_tt, Wr_tt, b_tt, xp, wdad);
    float a2 = gat_wave(d, 2, lane, ptr, cnt, aux, payload, hs_dv, Wr_dv, b_dv, xp, wdad);

    // LayerNorm over 204 = 12 (x) + 3*64, fully in-wave
    float sum = a0 + a1 + a2 + xl;
    float sq  = a0 * a0 + a1 * a1 + a2 * a2 + xl * xl;
    #pragma unroll
    for (int off = 1; off < 64; off <<= 1) {
        sum += __shfl_xor(sum, off, 64);
        sq  += __shfl_xor(sq, off, 64);
    }
    float mu = sum * (1.f / 204.f);
    float rstd = rsqrtf(sq * (1.f / 204.f) - mu * mu + 1e-5f);

    float* op = out + (size_t)d * 204;
    if (lane < 12) {
        float y = (xl - mu) * rstd * ln_g[lane] + ln_b[lane];
        op[lane] = y > 0.f ? y : 0.01f * y;
    }
    {
        float y = (a0 - mu) * rstd * ln_g[12 + lane] + ln_b[12 + lane];
        op[12 + lane] = y > 0.f ? y : 0.01f * y;
    }
    {
        float y = (a1 - mu) * rstd * ln_g[76 + lane] + ln_b[76 + lane];
        op[76 + lane] = y > 0.f ? y : 0.01f * y;
    }
    {
        float y = (a2 - mu) * rstd * ln_g[140 + lane] + ln_b[140 + lane];
        op[140 + lane] = y > 0.f ? y : 0.01f * y;
    }
}

extern "C" void kernel_launch(void* const* d_in, const int* in_sizes, int n_in,
                              void* d_out, int out_size, void* d_ws, size_t ws_size,
                              hipStream_t stream) {
    const float* x_tasks   = (const float*)d_in[0];
    const float* x_data    = (const float*)d_in[1];
    const float* x_devices = (const float*)d_in[2];
    const int*   src_td = (const int*)d_in[3];
    const int*   dst_td = (const int*)d_in[4];
    const float* eattr_td = (const float*)d_in[5];
    const int*   src_tt = (const int*)d_in[6];
    const int*   dst_tt = (const int*)d_in[7];
    const float* eattr_tt = (const float*)d_in[8];
    const int*   src_dv = (const int*)d_in[9];
    const int*   dst_dv = (const int*)d_in[10];
    const float* eattr_dv = (const float*)d_in[11];
    const float* Ws_td = (const float*)d_in[12];
    const float* Wd_td = (const float*)d_in[13];
    const float* We_td = (const float*)d_in[14];
    const float* as_td = (const float*)d_in[15];
    const float* ad_td = (const float*)d_in[16];
    const float* ae_td = (const float*)d_in[17];
    const float* Wr_td = (const float*)d_in[18];
    const float* b_td  = (const float*)d_in[19];
    const float* Ws_tt = (const float*)d_in[20];
    const float* Wd_tt = (const float*)d_in[21];
    const float* We_tt = (const float*)d_in[22];
    const float* as_tt = (const float*)d_in[23];
    const float* ad_tt = (const float*)d_in[24];
    const float* ae_tt = (const float*)d_in[25];
    const float* Wr_tt = (const float*)d_in[26];
    const float* b_tt  = (const float*)d_in[27];
    const float* Ws_dv = (const float*)d_in[28];
    const float* Wd_dv = (const float*)d_in[29];
    const float* We_dv = (const float*)d_in[30];
    const float* as_dv = (const float*)d_in[31];
    const float* ad_dv = (const float*)d_in[32];
    const float* ae_dv = (const float*)d_in[33];
    const float* Wr_dv = (const float*)d_in[34];
    const float* b_dv  = (const float*)d_in[35];
    const float* ln_g  = (const float*)d_in[36];
    const float* ln_b  = (const float*)d_in[37];

    float* ws = (float*)d_ws;
    float* hs_td = ws + OFF_HS_TD;
    float* hs_tt = ws + OFF_HS_TT;
    float* hs_dv = ws + OFF_HS_DV;
    float* ss_td = ws + OFF_SS_TD;
    float* ss_tt = ws + OFF_SS_TT;
    float* ss_dv = ws + OFF_SS_DV;
    float* wdad  = ws + OFF_WDAD;
    float* wea   = ws + OFF_WEA;
    int*   cnt   = (int*)(ws + OFF_CNT);
    int*   ptr   = (int*)(ws + OFF_PTR);
    int*   aux   = (int*)(ws + OFF_AUX);
    Payload* pay = (Payload*)(ws + OFF_PAY);

    float* outp = (float*)d_out;

    hipMemsetAsync(cnt, 0, SCAN_N * sizeof(int), stream);

    prep_kernel<<<1, 64, 0, stream>>>(Wd_td, ad_td, Wd_tt, ad_tt, Wd_dv, ad_dv,
                                      We_td, ae_td, We_tt, ae_tt, We_dv, ae_dv,
                                      wdad, wea);

    pre_kernel<<<PRE_B, 256, 0, stream>>>(
        x_data, x_tasks, x_devices,
        Ws_td, as_td, Ws_tt, as_tt, Ws_dv, as_dv,
        hs_td, ss_td, hs_tt, ss_tt, hs_dv, ss_dv,
        dst_td, dst_tt, dst_dv, cnt);

    scan1<<<SCAN_BLOCKS, 256, 0, stream>>>(cnt, ptr, aux, SCAN_N);
    scan2<<<1, 256, 0, stream>>>(aux, SCAN_BLOCKS);

    scatter_all<<<(E_ALL + 255) / 256, 256, 0, stream>>>(
        src_td, dst_td, eattr_td, src_tt, dst_tt, eattr_tt, src_dv, dst_dv, eattr_dv,
        wea, ss_td, ss_tt, ss_dv, ptr, aux, pay);

    fused_node_kernel<<<(N_TASKS * 64 + 255) / 256, 256, 0, stream>>>(
        x_tasks, ptr, cnt, aux, pay, hs_td, hs_tt, hs_dv, wdad,
        Wr_td, Wr_tt, Wr_dv, b_td, b_tt, b_dv, ln_g, ln_b, outp);
}

// Round 7
// 745.068 us; speedup vs baseline: 1.1355x; 1.0658x over previous
//
#include <hip/hip_runtime.h>
#include <math.h>

#define N_TASKS 200000
#define N_DATA  100000
#define N_DEV   4
#define E_TD    800000
#define E_TT    1600000
#define E_DV    800000
#define E_ALL   (E_TD + E_TT + E_DV)

struct __align__(8) Payload { int src; float scal; };  // scal = exp(leaky(full logit))

// ---- workspace layout (units: 4-byte words) — IDENTICAL footprint to the
// round-4/6 passing kernels (ends at OFF_PAY + 2*E_ALL = 108.4 MB).
// Extra scratch (edge ranks, sdv) lives in D_OUT, which is untouched until
// fused_node_kernel fully overwrites it at the end.
#define OFF_HS_TD   0                          // 100000*64
#define OFF_HS_TT   (OFF_HS_TD + 6400000)      // 200000*64
#define OFF_HS_DV   (OFF_HS_TT + 12800000)     // 4*64 -> 256
#define OFF_SS_TD   (OFF_HS_DV + 256)          // 100000
#define OFF_SS_TT   (OFF_SS_TD + 100000)       // 200000
#define OFF_SS_DV   (OFF_SS_TT + 200000)       // 4 -> 8
#define OFF_WDAD    (OFF_SS_DV + 8)            // 3*12 -> 64
#define OFF_WEA     (OFF_WDAD + 64)            // 6 -> 8
#define OFF_CNT     (OFF_WEA + 8)              // 3*N_TASKS = 600000
#define OFF_PTR     (OFF_CNT + 600000)         // 600000
#define OFF_AUX     (OFF_PTR + 600000)         // 1024
#define OFF_PAY     (OFF_AUX + 1024)           // 3.2M payloads * 2 words
#define SCAN_N      600000
#define SCAN_BLOCKS ((SCAN_N + 1023) / 1024)   // 586

// pre_kernel grid partition — histogram FIRST (latency-bound long pole).
#define CNT_B   12500                          // E_ALL/256
#define HS_TD_B 25000                          // N_DATA*64/256
#define HS_TT_B 50000                          // N_TASKS*64/256
#define PRE_B   (CNT_B + HS_TD_B + HS_TT_B + 1)

// scan1 grid: scan blocks + sdv blocks (sdv = x_tasks @ wdad per relation)
#define SDV_B   782                            // ceil(N_TASKS/256)

// prep grid: block 0 folds weights; blocks 1.. zero cnt (replaces memset)
#define PREP_B  (1 + SCAN_BLOCKS)

// Fold Wd@a_d (per relation, 12 floats) and We@a_e (3+1+2 floats) once.
// Blocks 1..586 zero the cnt array (absorbs the old hipMemsetAsync).
__global__ __launch_bounds__(256) void prep_kernel(
                            const float* Wd_td, const float* ad_td,
                            const float* Wd_tt, const float* ad_tt,
                            const float* Wd_dv, const float* ad_dv,
                            const float* We_td, const float* ae_td,
                            const float* We_tt, const float* ae_tt,
                            const float* We_dv, const float* ae_dv,
                            float* wdad, float* wea, int* cnt) {
    int b = blockIdx.x, t = threadIdx.x;
    if (b > 0) {
        int base = (b - 1) * 1024 + t * 4;
        #pragma unroll
        for (int k = 0; k < 4; ++k)
            if (base + k < SCAN_N) cnt[base + k] = 0;
        return;
    }
    if (t < 36) {
        int r = t / 12, k = t % 12;
        const float* Wd = r == 0 ? Wd_td : (r == 1 ? Wd_tt : Wd_dv);
        const float* ad = r == 0 ? ad_td : (r == 1 ? ad_tt : ad_dv);
        float acc = 0.f;
        for (int c = 0; c < 64; ++c) acc += Wd[k * 64 + c] * ad[c];
        wdad[r * 12 + k] = acc;
    } else if (t < 42) {
        int i = t - 36;
        int r, k;
        if (i < 3)      { r = 0; k = i; }
        else if (i < 4) { r = 1; k = 0; }
        else            { r = 2; k = i - 4; }
        const float* We = r == 0 ? We_td : (r == 1 ? We_tt : We_dv);
        const float* ae = r == 0 ? ae_td : (r == 1 ? ae_tt : ae_dv);
        float acc = 0.f;
        for (int c = 0; c < 64; ++c) acc += We[k * 64 + c] * ae[c];
        wea[i] = acc;
    }
}

// hs = x_src @ Ws  [Ns,64]; ss = hs @ a_s  [Ns]. One wave per source node.
template <int DS>
__device__ __forceinline__ void hs_body(const float* __restrict__ x, int Ns,
                                        const float* __restrict__ Ws, const float* __restrict__ a_s,
                                        float* __restrict__ hs, float* __restrict__ ss,
                                        int blk, int tid) {
    int gid = blk * 256 + tid;
    int s = gid >> 6;
    int lane = gid & 63;
    if (s >= Ns) return;
    float xv[DS];
    #pragma unroll
    for (int k = 0; k < DS; ++k) xv[k] = x[(size_t)s * DS + k];
    float acc = 0.f;
    #pragma unroll
    for (int k = 0; k < DS; ++k) acc = fmaf(xv[k], Ws[k * 64 + lane], acc);
    hs[(size_t)s * 64 + lane] = acc;
    float t = acc * a_s[lane];
    for (int off = 32; off; off >>= 1) t += __shfl_down(t, off, 64);
    if (lane == 0) ss[s] = t;
}

// Fused pre-pass: merged dst histogram + hs GEMVs for all 3 relations.
// The histogram atomic's RETURN VALUE is each edge's within-segment rank —
// stored to rank_buf (coalesced) so scatter_all needs NO atomics at all.
__global__ __launch_bounds__(256) void pre_kernel(
    const float* __restrict__ x_data, const float* __restrict__ x_tasks, const float* __restrict__ x_devices,
    const float* __restrict__ Ws_td, const float* __restrict__ as_td,
    const float* __restrict__ Ws_tt, const float* __restrict__ as_tt,
    const float* __restrict__ Ws_dv, const float* __restrict__ as_dv,
    float* __restrict__ hs_td, float* __restrict__ ss_td,
    float* __restrict__ hs_tt, float* __restrict__ ss_tt,
    float* __restrict__ hs_dv, float* __restrict__ ss_dv,
    const int* __restrict__ dst_td, const int* __restrict__ dst_tt, const int* __restrict__ dst_dv,
    int* __restrict__ cnt, int* __restrict__ rank_buf) {
    int b = blockIdx.x, tid = threadIdx.x;
    if (b < CNT_B) {
        int i = b * 256 + tid;
        int dseg;
        if (i < E_TD)               dseg = dst_td[i];
        else if (i < E_TD + E_TT)   dseg = N_TASKS + dst_tt[i - E_TD];
        else if (i < E_ALL)         dseg = 2 * N_TASKS + dst_dv[i - E_TD - E_TT];
        else return;
        rank_buf[i] = atomicAdd(&cnt[dseg], 1);
        return;
    }
    b -= CNT_B;
    if (b < HS_TD_B) { hs_body<5>(x_data, N_DATA, Ws_td, as_td, hs_td, ss_td, b, tid); return; }
    b -= HS_TD_B;
    if (b < HS_TT_B) { hs_body<12>(x_tasks, N_TASKS, Ws_tt, as_tt, hs_tt, ss_tt, b, tid); return; }
    b -= HS_TT_B;
    hs_body<12>(x_devices, N_DEV, Ws_dv, as_dv, hs_dv, ss_dv, 0, tid);
}

// ---- 2-kernel exclusive scan over 600000 ints (block-local; aux folds the
// per-block base in consumers). Extra blocks compute sdv = x_tasks@wdad.
__global__ __launch_bounds__(256) void scan1(
    const int* __restrict__ cnt, int* __restrict__ ptr,
    int* __restrict__ aux, int n,
    const float* __restrict__ x_tasks, const float* __restrict__ wdad,
    float* __restrict__ sdv) {
    __shared__ int s[256];
    int b = blockIdx.x, t = threadIdx.x;
    if (b >= SCAN_BLOCKS) {
        int d = (b - SCAN_BLOCKS) * 256 + t;
        if (d < N_TASKS) {
            float xv[12];
            #pragma unroll
            for (int k = 0; k < 12; ++k) xv[k] = x_tasks[(size_t)d * 12 + k];
            #pragma unroll
            for (int r = 0; r < 3; ++r) {
                float acc = 0.f;
                #pragma unroll
                for (int k = 0; k < 12; ++k) acc = fmaf(xv[k], wdad[r * 12 + k], acc);
                sdv[r * N_TASKS + d] = acc;
            }
        }
        return;
    }
    int base = b * 1024 + t * 4;
    int v0 = base + 0 < n ? cnt[base + 0] : 0;
    int v1 = base + 1 < n ? cnt[base + 1] : 0;
    int v2 = base + 2 < n ? cnt[base + 2] : 0;
    int v3 = base + 3 < n ? cnt[base + 3] : 0;
    int tsum = v0 + v1 + v2 + v3;
    s[t] = tsum;
    __syncthreads();
    for (int off = 1; off < 256; off <<= 1) {
        int x = (t >= off) ? s[t - off] : 0;
        __syncthreads();
        s[t] += x;
        __syncthreads();
    }
    int p = s[t] - tsum;  // exclusive prefix within block
    if (t == 255) aux[b] = s[255];
    if (base + 0 < n) ptr[base + 0] = p; p += v0;
    if (base + 1 < n) ptr[base + 1] = p; p += v1;
    if (base + 2 < n) ptr[base + 2] = p; p += v2;
    if (base + 3 < n) ptr[base + 3] = p;
}

__global__ void scan2(int* __restrict__ aux, int nb) {
    __shared__ int s[256];
    int t = threadIdx.x;
    int carry = 0;
    for (int base = 0; base < nb; base += 256) {
        int i = base + t;
        int v = i < nb ? aux[i] : 0;
        s[t] = v;
        __syncthreads();
        for (int off = 1; off < 256; off <<= 1) {
            int x = (t >= off) ? s[t - off] : 0;
            __syncthreads();
            s[t] += x;
            __syncthreads();
        }
        int excl = s[t] - v + carry;
        if (i < nb) aux[i] = excl;
        int total = s[255];
        __syncthreads();
        carry += total;
    }
}

// ATOMIC-FREE scatter: pos = start[dseg] + precomputed rank. Computes the
// full edge weight w = exp(leaky(ss[src] + sdv[dseg] + ea@wea)) here —
// this kernel is memory-latency bound with slack, fused has VALU pressure.
__global__ void scatter_all(const int* __restrict__ src_td, const int* __restrict__ dst_td, const float* __restrict__ ea_td,
                            const int* __restrict__ src_tt, const int* __restrict__ dst_tt, const float* __restrict__ ea_tt,
                            const int* __restrict__ src_dv, const int* __restrict__ dst_dv, const float* __restrict__ ea_dv,
                            const float* __restrict__ wea,
                            const float* __restrict__ ss_td, const float* __restrict__ ss_tt, const float* __restrict__ ss_dv,
                            const int* __restrict__ ptr, const int* __restrict__ aux,
                            const int* __restrict__ rank_buf, const float* __restrict__ sdv,
                            Payload* __restrict__ payload) {
    int i = blockIdx.x * blockDim.x + threadIdx.x;
    if (i >= E_ALL) return;
    int s, dseg;
    float sc;
    if (i < E_TD) {
        int e = i;
        sc = ea_td[(size_t)e * 3 + 0] * wea[0] + ea_td[(size_t)e * 3 + 1] * wea[1] + ea_td[(size_t)e * 3 + 2] * wea[2];
        s = src_td[e];
        sc += ss_td[s];
        dseg = dst_td[e];
    } else if (i < E_TD + E_TT) {
        int e = i - E_TD;
        sc = ea_tt[e] * wea[3];
        s = src_tt[e];
        sc += ss_tt[s];
        dseg = N_TASKS + dst_tt[e];
    } else {
        int e = i - E_TD - E_TT;
        sc = ea_dv[(size_t)e * 2 + 0] * wea[4] + ea_dv[(size_t)e * 2 + 1] * wea[5];
        s = src_dv[e];
        sc += ss_dv[s];
        dseg = 2 * N_TASKS + dst_dv[e];
    }
    sc += sdv[dseg];                       // L2-resident 4B gather
    float lg = sc > 0.f ? sc : 0.2f * sc;  // leaky_relu(logit, 0.2)
    int pos = ptr[dseg] + aux[dseg >> 10] + rank_buf[i];   // NO atomic
    Payload p; p.src = s; p.scal = __expf(lg);
    payload[pos] = p;
}

// Per-relation GAT aggregation for ONE node by ONE wave, channel = lane.
// (Round-4 proven structure.) Weights precomputed: loop is pure gather+FMA;
// denominator accumulates identically in all lanes (weight is wave-uniform).
__device__ __forceinline__ float gat_wave(
    int d, int r, int lane,
    const int* __restrict__ ptr, const int* __restrict__ cnt, const int* __restrict__ aux,
    const Payload* __restrict__ payload,
    const float* __restrict__ hs, const float* __restrict__ Wr, const float* __restrict__ bb,
    const float* __restrict__ xp) {
    int idx = r * N_TASKS + d;
    int beg = ptr[idx] + aux[idx >> 10];   // ptr = block-local START; aux folds base
    int end = beg + cnt[idx];
    float acc = 0.f, wsum = 0.f;
    #pragma unroll 4
    for (int e = beg; e < end; ++e) {
        Payload p = payload[e];            // wave-uniform -> scalar load
        acc = fmaf(p.scal, hs[(size_t)p.src * 64 + lane], acc);
        wsum += p.scal;
    }
    // residual + bias, channel = lane
    float res = bb[lane];
    #pragma unroll
    for (int k = 0; k < 12; ++k) res = fmaf(xp[k], Wr[k * 64 + lane], res);
    return acc / (wsum + 1e-16f) + res;
}

// One WAVE per task node (4 nodes per 256-thread block). No LDS, no barriers.
// LayerNorm over 204 channels entirely in-wave via butterfly shuffles.
__global__ __launch_bounds__(256) void fused_node_kernel(
    const float* __restrict__ x_tasks,
    const int* __restrict__ ptr, const int* __restrict__ cnt, const int* __restrict__ aux,
    const Payload* __restrict__ payload,
    const float* __restrict__ hs_td, const float* __restrict__ hs_tt, const float* __restrict__ hs_dv,
    const float* __restrict__ Wr_td, const float* __restrict__ Wr_tt, const float* __restrict__ Wr_dv,
    const float* __restrict__ b_td, const float* __restrict__ b_tt, const float* __restrict__ b_dv,
    const float* __restrict__ ln_g, const float* __restrict__ ln_b,
    float* __restrict__ out) {
    int wid = (blockIdx.x * blockDim.x + threadIdx.x) >> 6;
    if (wid >= N_TASKS) return;
    int d = __builtin_amdgcn_readfirstlane(wid);  // force SGPR -> scalar loads
    int lane = threadIdx.x & 63;

    const float* xp = x_tasks + (size_t)d * 12;   // uniform base
    float xl = lane < 12 ? xp[lane] : 0.f;        // per-lane copy for LN

    float a0 = gat_wave(d, 0, lane, ptr, cnt, aux, payload, hs_td, Wr_td, b_td, xp);
    float a1 = gat_wave(d, 1, lane, ptr, cnt, aux, payload, hs_tt, Wr_tt, b_tt, xp);
    float a2 = gat_wave(d, 2, lane, ptr, cnt, aux, payload, hs_dv, Wr_dv, b_dv, xp);

    // LayerNorm over 204 = 12 (x) + 3*64, fully in-wave
    float sum = a0 + a1 + a2 + xl;
    float sq  = a0 * a0 + a1 * a1 + a2 * a2 + xl * xl;
    #pragma unroll
    for (int off = 1; off < 64; off <<= 1) {
        sum += __shfl_xor(sum, off, 64);
        sq  += __shfl_xor(sq, off, 64);
    }
    float mu = sum * (1.f / 204.f);
    float rstd = rsqrtf(sq * (1.f / 204.f) - mu * mu + 1e-5f);

    float* op = out + (size_t)d * 204;
    if (lane < 12) {
        float y = (xl - mu) * rstd * ln_g[lane] + ln_b[lane];
        op[lane] = y > 0.f ? y : 0.01f * y;
    }
    {
        float y = (a0 - mu) * rstd * ln_g[12 + lane] + ln_b[12 + lane];
        op[12 + lane] = y > 0.f ? y : 0.01f * y;
    }
    {
        float y = (a1 - mu) * rstd * ln_g[76 + lane] + ln_b[76 + lane];
        op[76 + lane] = y > 0.f ? y : 0.01f * y;
    }
    {
        float y = (a2 - mu) * rstd * ln_g[140 + lane] + ln_b[140 + lane];
        op[140 + lane] = y > 0.f ? y : 0.01f * y;
    }
}

extern "C" void kernel_launch(void* const* d_in, const int* in_sizes, int n_in,
                              void* d_out, int out_size, void* d_ws, size_t ws_size,
                              hipStream_t stream) {
    const float* x_tasks   = (const float*)d_in[0];
    const float* x_data    = (const float*)d_in[1];
    const float* x_devices = (const float*)d_in[2];
    const int*   src_td = (const int*)d_in[3];
    const int*   dst_td = (const int*)d_in[4];
    const float* eattr_td = (const float*)d_in[5];
    const int*   src_tt = (const int*)d_in[6];
    const int*   dst_tt = (const int*)d_in[7];
    const float* eattr_tt = (const float*)d_in[8];
    const int*   src_dv = (const int*)d_in[9];
    const int*   dst_dv = (const int*)d_in[10];
    const float* eattr_dv = (const float*)d_in[11];
    const float* Ws_td = (const float*)d_in[12];
    const float* Wd_td = (const float*)d_in[13];
    const float* We_td = (const float*)d_in[14];
    const float* as_td = (const float*)d_in[15];
    const float* ad_td = (const float*)d_in[16];
    const float* ae_td = (const float*)d_in[17];
    const float* Wr_td = (const float*)d_in[18];
    const float* b_td  = (const float*)d_in[19];
    const float* Ws_tt = (const float*)d_in[20];
    const float* Wd_tt = (const float*)d_in[21];
    const float* We_tt = (const float*)d_in[22];
    const float* as_tt = (const float*)d_in[23];
    const float* ad_tt = (const float*)d_in[24];
    const float* ae_tt = (const float*)d_in[25];
    const float* Wr_tt = (const float*)d_in[26];
    const float* b_tt  = (const float*)d_in[27];
    const float* Ws_dv = (const float*)d_in[28];
    const float* Wd_dv = (const float*)d_in[29];
    const float* We_dv = (const float*)d_in[30];
    const float* as_dv = (const float*)d_in[31];
    const float* ad_dv = (const float*)d_in[32];
    const float* ae_dv = (const float*)d_in[33];
    const float* Wr_dv = (const float*)d_in[34];
    const float* b_dv  = (const float*)d_in[35];
    const float* ln_g  = (const float*)d_in[36];
    const float* ln_b  = (const float*)d_in[37];

    float* ws = (float*)d_ws;
    float* hs_td = ws + OFF_HS_TD;
    float* hs_tt = ws + OFF_HS_TT;
    float* hs_dv = ws + OFF_HS_DV;
    float* ss_td = ws + OFF_SS_TD;
    float* ss_tt = ws + OFF_SS_TT;
    float* ss_dv = ws + OFF_SS_DV;
    float* wdad  = ws + OFF_WDAD;
    float* wea   = ws + OFF_WEA;
    int*   cnt   = (int*)(ws + OFF_CNT);
    int*   ptr   = (int*)(ws + OFF_PTR);
    int*   aux   = (int*)(ws + OFF_AUX);
    Payload* pay = (Payload*)(ws + OFF_PAY);

    float* outp = (float*)d_out;
    // d_out doubles as scratch until fused_node_kernel overwrites it:
    int*   rank_buf = (int*)d_out;             // E_ALL u32 = 12.8 MB
    float* sdv      = (float*)d_out + E_ALL;   // 600000 f32 = 2.4 MB (of 163 MB)

    prep_kernel<<<PREP_B, 256, 0, stream>>>(Wd_td, ad_td, Wd_tt, ad_tt, Wd_dv, ad_dv,
                                            We_td, ae_td, We_tt, ae_tt, We_dv, ae_dv,
                                            wdad, wea, cnt);

    pre_kernel<<<PRE_B, 256, 0, stream>>>(
        x_data, x_tasks, x_devices,
        Ws_td, as_td, Ws_tt, as_tt, Ws_dv, as_dv,
        hs_td, ss_td, hs_tt, ss_tt, hs_dv, ss_dv,
        dst_td, dst_tt, dst_dv, cnt, rank_buf);

    scan1<<<SCAN_BLOCKS + SDV_B, 256, 0, stream>>>(cnt, ptr, aux, SCAN_N, x_tasks, wdad, sdv);
    scan2<<<1, 256, 0, stream>>>(aux, SCAN_BLOCKS);

    scatter_all<<<(E_ALL + 255) / 256, 256, 0, stream>>>(
        src_td, dst_td, eattr_td, src_tt, dst_tt, eattr_tt, src_dv, dst_dv, eattr_dv,
        wea, ss_td, ss_tt, ss_dv, ptr, aux, rank_buf, sdv, pay);

    fused_node_kernel<<<(N_TASKS * 64 + 255) / 256, 256, 0, stream>>>(
        x_tasks, ptr, cnt, aux, pay, hs_td, hs_tt, hs_dv,
        Wr_td, Wr_tt, Wr_dv, b_td, b_tt, b_dv, ln_g, ln_b, outp);
}